// Round 14
// baseline (309.723 us; speedup 1.0000x reference)
//
#include <hip/hip_runtime.h>

#define NN 100000
#define NE 1600000
#define BN_EPS 1e-5f

#define BSH 7             // bucket shift: 128 nodes per bucket
#define NBUC 782          // ceil(NN/128)
#define CBLK 391          // edge-chunk blocks (x4096 >= NE)
#define AEPB 4096         // edges per chunk block
#define XS_BLOCKS 782     // NN*8 / 1024 rounded up
#define WPREP_BLOCKS 32   // 32768 / 1024

typedef _Float16 h2 __attribute__((ext_vector_type(2)));
typedef _Float16 f16x8 __attribute__((ext_vector_type(8)));
typedef float f32x4 __attribute__((ext_vector_type(4)));

static __device__ __forceinline__ unsigned int pack2f(float a, float b) {
    h2 p; p[0] = (_Float16)a; p[1] = (_Float16)b;
    return __builtin_bit_cast(unsigned int, p);
}
static __device__ __forceinline__ float2 unpack2f(unsigned int u) {
    h2 p = __builtin_bit_cast(h2, u);
    return make_float2((float)p[0], (float)p[1]);
}
static __device__ __forceinline__ float unpack1f(unsigned short u) {
    return (float)__builtin_bit_cast(_Float16, u);
}
static __device__ __forceinline__ unsigned short pack1f(float a) {
    return __builtin_bit_cast(unsigned short, (_Float16)a);
}

// ======== A: per-chunk bucket histogram (+ x->fp16 cast, W-frag prep) ========
__global__ __launch_bounds__(1024) void k_hist_cast(
        const int* __restrict__ dst, int* __restrict__ g_hist,
        const float* __restrict__ x, unsigned short* __restrict__ xs,
        const float* __restrict__ W1, const float* __restrict__ W2,
        const float* __restrict__ W3, unsigned short* __restrict__ Wf1,
        unsigned short* __restrict__ Wf2, unsigned short* __restrict__ Wf3) {
    int b = blockIdx.x, t = threadIdx.x;
    if (b < CBLK) {
        __shared__ int h[NBUC];
        for (int i = t; i < NBUC; i += 1024) h[i] = 0;
        __syncthreads();
        int e0 = b * AEPB;
#pragma unroll
        for (int j = 0; j < 4; ++j) {
            int e = e0 + t + j * 1024;
            if (e < NE) {
                int d = __builtin_nontemporal_load(&dst[e]);
                atomicAdd(&h[d >> BSH], 1);
            }
        }
        __syncthreads();
        for (int i = t; i < NBUC; i += 1024) g_hist[i * CBLK + b] = h[i];  // bucket-major
    } else if (b < CBLK + XS_BLOCKS) {
        int i = (b - CBLK) * 1024 + t;               // group of 8 cols
        if (i < NN * 8) {
            int row = i >> 3, c8 = i & 7;
            const float4* xp = (const float4*)(x + (size_t)row * 64 + c8 * 8);
            float4 f0 = xp[0], f1 = xp[1];
            uint4 o;
            o.x = pack2f(f0.x, f0.y); o.y = pack2f(f0.z, f0.w);
            o.z = pack2f(f1.x, f1.y); o.w = pack2f(f1.z, f1.w);
            *(uint4*)(xs + (size_t)row * 64 + c8 * 8) = o;   // unscaled; D scales by dinv
        }
    } else {
        int i = (b - CBLK - XS_BLOCKS) * 1024 + t;   // 0..32767
        if (i < 8192) {            // Wf1: K=64 (KS=2), M=128 (CT=8)
            int j = i & 7, lane = (i >> 3) & 63, ksct = i >> 9;
            int ks = ksct & 1, ct = ksct >> 1;
            int n = ct * 16 + (lane & 15);
            int k = ks * 32 + (lane >> 4) * 8 + j;
            Wf1[i] = pack1f(W1[k * 128 + n]);
        } else if (i < 24576) {    // Wf2: K=128 (KS=4), M=128 (CT=8)
            int q = i - 8192;
            int j = q & 7, lane = (q >> 3) & 63, ksct = q >> 9;
            int ks = ksct & 3, ct = ksct >> 2;
            int n = ct * 16 + (lane & 15);
            int k = ks * 32 + (lane >> 4) * 8 + j;
            Wf2[q] = pack1f(W2[k * 128 + n]);
        } else if (i < 32768) {    // Wf3: K=128 (KS=4), M=64 (CT=4)
            int q = i - 24576;
            int j = q & 7, lane = (q >> 3) & 63, ksct = q >> 9;
            int ks = ksct & 3, ct = ksct >> 2;
            int n = ct * 16 + (lane & 15);
            int k = ks * 32 + (lane >> 4) * 8 + j;
            Wf3[q] = pack1f(W3[k * 64 + n]);
        }
    }
}

// ======== B1: exclusive scan of each bucket's 391 chunk-counts ========
__global__ __launch_bounds__(512) void k_scan_cols(int* __restrict__ g_hist,
                                                   int* __restrict__ btot) {
    __shared__ int s[512];
    int k = blockIdx.x, t = threadIdx.x;
    int v = (t < CBLK) ? g_hist[k * CBLK + t] : 0;
    s[t] = v;
    for (int o = 1; o < 512; o <<= 1) {
        __syncthreads();
        int xl = (t >= o) ? s[t - o] : 0;
        __syncthreads();
        s[t] += xl;
    }
    __syncthreads();
    if (t < CBLK) g_hist[k * CBLK + t] = s[t] - v;   // exclusive within bucket
    if (t == CBLK - 1) btot[k] = s[t];               // bucket total
}

// ======== B2: exclusive scan of bucket totals -> bucket bases ========
__global__ __launch_bounds__(1024) void k_scan_buckets(const int* __restrict__ btot,
                                                       int* __restrict__ bb,
                                                       int* __restrict__ degoff) {
    __shared__ int s[1024];
    int t = threadIdx.x;
    int v = (t < NBUC) ? btot[t] : 0;
    s[t] = v;
    for (int o = 1; o < 1024; o <<= 1) {
        __syncthreads();
        int xl = (t >= o) ? s[t - o] : 0;
        __syncthreads();
        s[t] += xl;
    }
    __syncthreads();
    if (t < NBUC) bb[t] = s[t] - v;
    if (t == 0) { bb[NBUC] = NE; degoff[NN] = NE; }
}

// ======== C: scatter edges into bucket-sorted order, packed word ========
// packed = (dst&127) << 20 | src   (src < 2^17 fits in 20 bits)
__global__ __launch_bounds__(1024) void k_scatter_edges(
        const int* __restrict__ src, const int* __restrict__ dst,
        const int* __restrict__ g_hist, const int* __restrict__ bb,
        int* __restrict__ sed) {
    __shared__ int cur[NBUC];
    int b = blockIdx.x, t = threadIdx.x;
    for (int i = t; i < NBUC; i += 1024) cur[i] = bb[i] + g_hist[i * CBLK + b];
    __syncthreads();
    int e0 = b * AEPB;
#pragma unroll
    for (int j = 0; j < 4; ++j) {
        int e = e0 + t + j * 1024;
        if (e < NE) {
            int d = __builtin_nontemporal_load(&dst[e]);
            int s = __builtin_nontemporal_load(&src[e]);
            int p = atomicAdd(&cur[d >> BSH], 1);
            sed[p] = ((d & 127) << 20) | s;   // stays in L2 -- D re-reads next
        }
    }
}

// ======== D: per-bucket count + scan + CSR fill + degoff/dinv + xs scale ========
__global__ __launch_bounds__(1024) void k_bucket_csr(
        const int* __restrict__ sed, const int* __restrict__ bb,
        int* __restrict__ csr, int* __restrict__ degoff,
        float* __restrict__ dinv, unsigned short* __restrict__ xs) {
    __shared__ int cnt[128], off[128];
    __shared__ float sdv[128];
    int k = blockIdx.x, t = threadIdx.x;
    int n0 = k << BSH;
    int ebeg = bb[k], eend = bb[k + 1];
    if (t < 128) cnt[t] = 0;
    __syncthreads();
    for (int e = ebeg + t; e < eend; e += 1024)
        atomicAdd(&cnt[((unsigned)sed[e]) >> 20], 1);
    __syncthreads();
    int c = (t < 128) ? cnt[t] : 0;
    if (t < 128) off[t] = c;
    for (int o = 1; o < 128; o <<= 1) {
        __syncthreads();
        int xl = (t < 128 && t >= o) ? off[t - o] : 0;
        __syncthreads();
        if (t < 128) off[t] += xl;
    }
    __syncthreads();
    if (t < 128) {
        int excl = off[t] - c;           // exclusive within bucket
        float d = rsqrtf((float)c + 1.0f);
        sdv[t] = d;
        int n = n0 + t;
        if (n < NN) {
            degoff[n] = ebeg + excl;
            dinv[n] = d;
        }
        cnt[t] = excl;                   // becomes cursor
    }
    __syncthreads();
    for (int e = ebeg + t; e < eend; e += 1024) {
        unsigned v = (unsigned)sed[e];
        int p = atomicAdd(&cnt[v >> 20], 1);
        csr[ebeg + p] = v & 0xFFFFF;     // ~8KB window per bucket: L2-local
    }
    // scale this bucket's xs rows in place: xs[n][:] *= dinv[n]
    // 128 rows x 8 uint4 = 1024 uint4 -> exactly one iteration.
    {
        int r = t >> 3;                  // row within bucket
        int n = n0 + r;
        if (n < NN) {
            float d = sdv[r];
            uint4* p = (uint4*)(xs + (size_t)n * 64) + (t & 7);
            uint4 v = *p;
            float2 q0 = unpack2f(v.x), q1 = unpack2f(v.y);
            float2 q2 = unpack2f(v.z), q3 = unpack2f(v.w);
            v.x = pack2f(q0.x * d, q0.y * d);
            v.y = pack2f(q1.x * d, q1.y * d);
            v.z = pack2f(q2.x * d, q2.y * d);
            v.w = pack2f(q3.x * d, q3.y * d);
            *p = v;
        }
    }
}

// ======== 64-wide gather (pre-scaled xs): agg = (sum xs[s] + xs[n]) * dinv[n] ========
__global__ __launch_bounds__(256) void k_gather64_f16(
        const unsigned short* __restrict__ xs, const int* __restrict__ off,
        const int* __restrict__ csr, const float* __restrict__ dinv,
        unsigned short* __restrict__ agg) {
    int n = blockIdx.x * 4 + (threadIdx.x >> 6);
    if (n >= NN) return;
    int lane = threadIdx.x & 63;

    int beg = off[n], end = off[n + 1];
    float a0 = 0.f, a1 = 0.f, a2 = 0.f, a3 = 0.f;
    int e = beg;
    for (; e + 8 <= end; e += 8) {
        int s0 = csr[e],     s1 = csr[e + 1], s2 = csr[e + 2], s3 = csr[e + 3];
        int s4 = csr[e + 4], s5 = csr[e + 5], s6 = csr[e + 6], s7 = csr[e + 7];
        unsigned short u0 = xs[(size_t)s0 * 64 + lane];
        unsigned short u1 = xs[(size_t)s1 * 64 + lane];
        unsigned short u2 = xs[(size_t)s2 * 64 + lane];
        unsigned short u3 = xs[(size_t)s3 * 64 + lane];
        unsigned short u4 = xs[(size_t)s4 * 64 + lane];
        unsigned short u5 = xs[(size_t)s5 * 64 + lane];
        unsigned short u6 = xs[(size_t)s6 * 64 + lane];
        unsigned short u7 = xs[(size_t)s7 * 64 + lane];
        a0 += unpack1f(u0); a1 += unpack1f(u1);
        a2 += unpack1f(u2); a3 += unpack1f(u3);
        a0 += unpack1f(u4); a1 += unpack1f(u5);
        a2 += unpack1f(u6); a3 += unpack1f(u7);
    }
    for (; e + 2 <= end; e += 2) {
        a0 += unpack1f(xs[(size_t)csr[e] * 64 + lane]);
        a1 += unpack1f(xs[(size_t)csr[e + 1] * 64 + lane]);
    }
    if (e < end) a0 += unpack1f(xs[(size_t)csr[e] * 64 + lane]);

    float v = (a0 + a1 + a2 + a3 + unpack1f(xs[(size_t)n * 64 + lane])) * dinv[n];
    agg[(size_t)n * 64 + lane] = pack1f(v);
}

// ======== 128-wide gather, fp16 in -> fp16 agg (unroll 8) ========
__global__ __launch_bounds__(256) void k_gather128_f16(
        const unsigned short* __restrict__ h1, const int* __restrict__ off,
        const int* __restrict__ csr, const float* __restrict__ dinv,
        unsigned short* __restrict__ agg) {
    int n = blockIdx.x * 4 + (threadIdx.x >> 6);
    if (n >= NN) return;
    int lane = threadIdx.x & 63;
    const unsigned int* h = (const unsigned int*)h1;   // half2 per lane

    int beg = off[n], end = off[n + 1];
    float ax = 0.f, ay = 0.f, bx = 0.f, by = 0.f;
    float cx = 0.f, cy = 0.f, dx = 0.f, dy = 0.f;
    int e = beg;
    for (; e + 8 <= end; e += 8) {
        int s0 = csr[e],     s1 = csr[e + 1], s2 = csr[e + 2], s3 = csr[e + 3];
        int s4 = csr[e + 4], s5 = csr[e + 5], s6 = csr[e + 6], s7 = csr[e + 7];
        unsigned int u0 = h[(size_t)s0 * 64 + lane];
        unsigned int u1 = h[(size_t)s1 * 64 + lane];
        unsigned int u2 = h[(size_t)s2 * 64 + lane];
        unsigned int u3 = h[(size_t)s3 * 64 + lane];
        unsigned int u4 = h[(size_t)s4 * 64 + lane];
        unsigned int u5 = h[(size_t)s5 * 64 + lane];
        unsigned int u6 = h[(size_t)s6 * 64 + lane];
        unsigned int u7 = h[(size_t)s7 * 64 + lane];
        float2 v0 = unpack2f(u0), v1 = unpack2f(u1), v2 = unpack2f(u2), v3 = unpack2f(u3);
        float2 v4 = unpack2f(u4), v5 = unpack2f(u5), v6 = unpack2f(u6), v7 = unpack2f(u7);
        ax += v0.x; ay += v0.y;  bx += v1.x; by += v1.y;
        cx += v2.x; cy += v2.y;  dx += v3.x; dy += v3.y;
        ax += v4.x; ay += v4.y;  bx += v5.x; by += v5.y;
        cx += v6.x; cy += v6.y;  dx += v7.x; dy += v7.y;
    }
    for (; e + 2 <= end; e += 2) {
        float2 v0 = unpack2f(h[(size_t)csr[e] * 64 + lane]);
        float2 v1 = unpack2f(h[(size_t)csr[e + 1] * 64 + lane]);
        ax += v0.x; ay += v0.y;  bx += v1.x; by += v1.y;
    }
    if (e < end) {
        float2 v0 = unpack2f(h[(size_t)csr[e] * 64 + lane]);
        ax += v0.x; ay += v0.y;
    }
    float2 self = unpack2f(h[(size_t)n * 64 + lane]);
    float dn = dinv[n];
    ((unsigned int*)agg)[(size_t)n * 64 + lane] =
        pack2f((ax + bx + cx + dx + self.x) * dn,
               (ay + by + cy + dy + self.y) * dn);
}

// ======== MFMA GEMM: out = epilogue(agg @ W) ========
template <int K, int M, int EPI>
__global__ __launch_bounds__(256) void k_gemm_mfma(
        const unsigned short* __restrict__ A, const unsigned short* __restrict__ Wf,
        const float* __restrict__ dinv, const float* __restrict__ bias,
        const float* __restrict__ g, const float* __restrict__ be,
        const float* __restrict__ mn, const float* __restrict__ vr,
        unsigned short* __restrict__ outp) {
    constexpr int KS = K / 32;
    constexpr int CT = M / 16;
    __shared__ __align__(16) unsigned short sWf[CT * KS * 64 * 8];
    __shared__ float sSc[M], sSh[M];

    int tid = threadIdx.x;
    {
        const uint4* s = (const uint4*)Wf;
        uint4* d = (uint4*)sWf;
        constexpr int W4 = CT * KS * 64;
#pragma unroll
        for (int i = tid; i < W4; i += 256) d[i] = s[i];
    }
    if constexpr (EPI == 1 || EPI == 2) {
        for (int c = tid; c < M; c += 256) {
            float s = g[c] * rsqrtf(vr[c] + BN_EPS);
            sSc[c] = s;
            sSh[c] = (bias[c] - mn[c]) * s + be[c];
        }
    }
    __syncthreads();

    int wave = tid >> 6, lane = tid & 63;
    int row0 = blockIdx.x * 64 + wave * 16;
    if (row0 >= NN) return;
    int r  = row0 + (lane & 15);
    int kq = lane >> 4;

    f16x8 bf[KS];
#pragma unroll
    for (int ks = 0; ks < KS; ++ks)
        bf[ks] = *(const f16x8*)(A + (size_t)r * K + ks * 32 + kq * 8);

    float dr = dinv[r];
    const f16x8* wfp = (const f16x8*)sWf;
#pragma unroll
    for (int ct = 0; ct < CT; ++ct) {
        f32x4 acc = {0.f, 0.f, 0.f, 0.f};
#pragma unroll
        for (int ks = 0; ks < KS; ++ks)
            acc = __builtin_amdgcn_mfma_f32_16x16x32_f16(
                wfp[(ct * KS + ks) * 64 + lane], bf[ks], acc, 0, 0, 0);

        int c4 = ct * 16 + kq * 4;
        unsigned short* op = outp + (size_t)r * M + c4;
        if constexpr (EPI == 1 || EPI == 2) {
            float v0 = fmaxf(acc[0] * sSc[c4 + 0] + sSh[c4 + 0], 0.f);
            float v1 = fmaxf(acc[1] * sSc[c4 + 1] + sSh[c4 + 1], 0.f);
            float v2 = fmaxf(acc[2] * sSc[c4 + 2] + sSh[c4 + 2], 0.f);
            float v3 = fmaxf(acc[3] * sSc[c4 + 3] + sSh[c4 + 3], 0.f);
            if constexpr (EPI == 1) { v0 *= dr; v1 *= dr; v2 *= dr; v3 *= dr; }
            uint2 o; o.x = pack2f(v0, v1); o.y = pack2f(v2, v3);
            *(uint2*)op = o;
        } else {
            uint2 o;
            o.x = pack2f(acc[0] * dr, acc[1] * dr);
            o.y = pack2f(acc[2] * dr, acc[3] * dr);
            *(uint2*)op = o;
        }
    }
}

// ======== final: gather fp16 + b3 + ReLU + (·Wo + bo) ========
__global__ __launch_bounds__(256) void k_gather_final_f16(
        const unsigned short* __restrict__ hs, const int* __restrict__ off,
        const int* __restrict__ csr, const float* __restrict__ dinv,
        const float* __restrict__ b, const float* __restrict__ Wo,
        const float* __restrict__ bo, float* __restrict__ out) {
    int n = blockIdx.x * 4 + (threadIdx.x >> 6);
    if (n >= NN) return;
    int lane = threadIdx.x & 63;

    int beg = off[n], end = off[n + 1];
    float a0 = 0.f, a1 = 0.f, a2 = 0.f, a3 = 0.f;
    int e = beg;
    for (; e + 8 <= end; e += 8) {
        int s0 = csr[e],     s1 = csr[e + 1], s2 = csr[e + 2], s3 = csr[e + 3];
        int s4 = csr[e + 4], s5 = csr[e + 5], s6 = csr[e + 6], s7 = csr[e + 7];
        a0 += unpack1f(hs[(size_t)s0 * 64 + lane]);
        a1 += unpack1f(hs[(size_t)s1 * 64 + lane]);
        a2 += unpack1f(hs[(size_t)s2 * 64 + lane]);
        a3 += unpack1f(hs[(size_t)s3 * 64 + lane]);
        a0 += unpack1f(hs[(size_t)s4 * 64 + lane]);
        a1 += unpack1f(hs[(size_t)s5 * 64 + lane]);
        a2 += unpack1f(hs[(size_t)s6 * 64 + lane]);
        a3 += unpack1f(hs[(size_t)s7 * 64 + lane]);
    }
    for (; e + 2 <= end; e += 2) {
        a0 += unpack1f(hs[(size_t)csr[e] * 64 + lane]);
        a1 += unpack1f(hs[(size_t)csr[e + 1] * 64 + lane]);
    }
    if (e < end) a0 += unpack1f(hs[(size_t)csr[e] * 64 + lane]);

    float val = (a0 + a1 + a2 + a3 + unpack1f(hs[(size_t)n * 64 + lane])) * dinv[n]
                + b[lane];
    val = fmaxf(val, 0.f) * Wo[lane];
#pragma unroll
    for (int o = 32; o > 0; o >>= 1) val += __shfl_down(val, o, 64);
    if (lane == 0) out[n] = val + bo[0];
}

extern "C" void kernel_launch(void* const* d_in, const int* in_sizes, int n_in,
                              void* d_out, int out_size, void* d_ws, size_t ws_size,
                              hipStream_t stream) {
    const float* x   = (const float*)d_in[0];
    const int*   ei  = (const int*)d_in[1];
    const int*   src = ei;
    const int*   dst = ei + NE;
    const float* W1  = (const float*)d_in[2];
    const float* b1  = (const float*)d_in[3];
    const float* g1  = (const float*)d_in[4];
    const float* be1 = (const float*)d_in[5];
    const float* m1  = (const float*)d_in[6];
    const float* v1  = (const float*)d_in[7];
    const float* W2  = (const float*)d_in[8];
    const float* b2  = (const float*)d_in[9];
    const float* g2  = (const float*)d_in[10];
    const float* be2 = (const float*)d_in[11];
    const float* m2  = (const float*)d_in[12];
    const float* v2  = (const float*)d_in[13];
    const float* W3  = (const float*)d_in[14];
    const float* b3  = (const float*)d_in[15];
    const float* Wo  = (const float*)d_in[16];
    const float* bo  = (const float*)d_in[17];
    float* out = (float*)d_out;

    char* ws = (char*)d_ws;
    float* dinv   = (float*)(ws + 0);                // 400,000 B
    int*   degoff = (int*)(ws + 400032);             // (N+1) ints
    int*   bb     = (int*)(ws + 800064);             // NBUC+1 ints (3,132 B)
    int*   btot   = (int*)(ws + 803264);             // NBUC ints (3,128 B)
    int*   g_hist = (int*)(ws + 806400);             // NBUC*CBLK ints = 1,223,048 B
    unsigned short* Wf1 = (unsigned short*)(ws + 2029500 + 4);  // align 16: use 2029504
    unsigned short* Wf2 = (unsigned short*)(ws + 2045888);  // 32,768 B
    unsigned short* Wf3 = (unsigned short*)(ws + 2078656);  // 16,384 B -> 2,095,040
    int*   csr    = (int*)(ws + 2095040);            // 6,400,000 B -> 8,495,040
    char*  S1     = ws + 8495040;                    // 51.2 MB: xs(f16) -> h1ps(f16) -> h2p(f16)
    char*  S2     = ws + 59695040;                   // 51.2 MB: sed -> aggX -> aggH1 -> hs3

    unsigned short* xs    = (unsigned short*)S1;
    unsigned short* h1ps  = (unsigned short*)S1;
    unsigned short* h2p   = (unsigned short*)S1;
    int*            sed   = (int*)S2;                // 6.4 MB packed edges (dead after D)
    unsigned short* aggX  = (unsigned short*)S2;
    unsigned short* aggH1 = (unsigned short*)S2;
    unsigned short* hs3   = (unsigned short*)S2;

    int gW = (NN + 3) / 4;
    int gG = (NN + 63) / 64;

    // ---- atomic-free CSR build: hist -> scans -> scatter(packed) -> per-bucket fill+scale ----
    k_hist_cast<<<CBLK + XS_BLOCKS + WPREP_BLOCKS, 1024, 0, stream>>>(
        dst, g_hist, x, xs, W1, W2, W3, Wf1, Wf2, Wf3);
    k_scan_cols<<<NBUC, 512, 0, stream>>>(g_hist, btot);
    k_scan_buckets<<<1, 1024, 0, stream>>>(btot, bb, degoff);
    k_scatter_edges<<<CBLK, 1024, 0, stream>>>(src, dst, g_hist, bb, sed);
    k_bucket_csr<<<NBUC, 1024, 0, stream>>>(sed, bb, csr, degoff, dinv, xs);

    // ---- layer 1: gather(xs pre-scaled) ; MFMA GEMM1 + BN + ReLU + *dinv ----
    k_gather64_f16<<<gW, 256, 0, stream>>>(xs, degoff, csr, dinv, aggX);
    k_gemm_mfma<64, 128, 1><<<gG, 256, 0, stream>>>(
        aggX, Wf1, dinv, b1, g1, be1, m1, v1, h1ps);

    // ---- layer 2: gather(h1ps) ; MFMA GEMM2 + BN + ReLU ----
    k_gather128_f16<<<gW, 256, 0, stream>>>(h1ps, degoff, csr, dinv, aggH1);
    k_gemm_mfma<128, 128, 2><<<gG, 256, 0, stream>>>(
        aggH1, Wf2, dinv, b2, g2, be2, m2, v2, h2p);

    // ---- layer 3: MFMA GEMM3 (*dinv) ; final gather + dot ----
    k_gemm_mfma<128, 64, 3><<<gG, 256, 0, stream>>>(
        h2p, Wf3, dinv, nullptr, nullptr, nullptr, nullptr, nullptr, hs3);
    k_gather_final_f16<<<gW, 256, 0, stream>>>(hs3, degoff, csr, dinv,
                                               b3, Wo, bo, out);
}

// Round 15
// 269.921 us; speedup vs baseline: 1.1475x; 1.1475x over previous
//
#include <hip/hip_runtime.h>

#define NN 100000
#define NE 1600000
#define BN_EPS 1e-5f

#define NBUC 196          // node buckets of 512 (99999>>9 = 195)
#define CBLK 391          // edge-chunk blocks (x4096 >= NE)
#define AEPB 4096         // edges per chunk block
#define XS_BLOCKS 782     // NN*8 / 1024 rounded up
#define WPREP_BLOCKS 32   // 32768 / 1024

typedef _Float16 h2 __attribute__((ext_vector_type(2)));
typedef _Float16 f16x8 __attribute__((ext_vector_type(8)));
typedef float f32x4 __attribute__((ext_vector_type(4)));

static __device__ __forceinline__ unsigned int pack2f(float a, float b) {
    h2 p; p[0] = (_Float16)a; p[1] = (_Float16)b;
    return __builtin_bit_cast(unsigned int, p);
}
static __device__ __forceinline__ float2 unpack2f(unsigned int u) {
    h2 p = __builtin_bit_cast(h2, u);
    return make_float2((float)p[0], (float)p[1]);
}
static __device__ __forceinline__ float unpack1f(unsigned short u) {
    return (float)__builtin_bit_cast(_Float16, u);
}
static __device__ __forceinline__ unsigned short pack1f(float a) {
    return __builtin_bit_cast(unsigned short, (_Float16)a);
}

// ======== A: per-chunk bucket histogram (+ x->fp16 cast, W-frag prep) ========
__global__ __launch_bounds__(1024) void k_hist_cast(
        const int* __restrict__ dst, int* __restrict__ g_hist,
        const float* __restrict__ x, unsigned short* __restrict__ xs,
        const float* __restrict__ W1, const float* __restrict__ W2,
        const float* __restrict__ W3, unsigned short* __restrict__ Wf1,
        unsigned short* __restrict__ Wf2, unsigned short* __restrict__ Wf3) {
    int b = blockIdx.x, t = threadIdx.x;
    if (b < CBLK) {
        __shared__ int h[NBUC];
        if (t < NBUC) h[t] = 0;
        __syncthreads();
        int e0 = b * AEPB;
#pragma unroll
        for (int j = 0; j < 4; ++j) {
            int e = e0 + t + j * 1024;
            if (e < NE) {
                int d = __builtin_nontemporal_load(&dst[e]);
                atomicAdd(&h[d >> 9], 1);
            }
        }
        __syncthreads();
        if (t < NBUC) g_hist[t * CBLK + b] = h[t];   // bucket-major
    } else if (b < CBLK + XS_BLOCKS) {
        int i = (b - CBLK) * 1024 + t;               // group of 8 cols
        if (i < NN * 8) {
            int row = i >> 3, c8 = i & 7;
            const float4* xp = (const float4*)(x + (size_t)row * 64 + c8 * 8);
            float4 f0 = xp[0], f1 = xp[1];
            uint4 o;
            o.x = pack2f(f0.x, f0.y); o.y = pack2f(f0.z, f0.w);
            o.z = pack2f(f1.x, f1.y); o.w = pack2f(f1.z, f1.w);
            *(uint4*)(xs + (size_t)row * 64 + c8 * 8) = o;   // unscaled; D scales by dinv
        }
    } else {
        int i = (b - CBLK - XS_BLOCKS) * 1024 + t;   // 0..32767
        if (i < 8192) {            // Wf1: K=64 (KS=2), M=128 (CT=8)
            int j = i & 7, lane = (i >> 3) & 63, ksct = i >> 9;
            int ks = ksct & 1, ct = ksct >> 1;
            int n = ct * 16 + (lane & 15);
            int k = ks * 32 + (lane >> 4) * 8 + j;
            Wf1[i] = pack1f(W1[k * 128 + n]);
        } else if (i < 24576) {    // Wf2: K=128 (KS=4), M=128 (CT=8)
            int q = i - 8192;
            int j = q & 7, lane = (q >> 3) & 63, ksct = q >> 9;
            int ks = ksct & 3, ct = ksct >> 2;
            int n = ct * 16 + (lane & 15);
            int k = ks * 32 + (lane >> 4) * 8 + j;
            Wf2[q] = pack1f(W2[k * 128 + n]);
        } else if (i < 32768) {    // Wf3: K=128 (KS=4), M=64 (CT=4)
            int q = i - 24576;
            int j = q & 7, lane = (q >> 3) & 63, ksct = q >> 9;
            int ks = ksct & 3, ct = ksct >> 2;
            int n = ct * 16 + (lane & 15);
            int k = ks * 32 + (lane >> 4) * 8 + j;
            Wf3[q] = pack1f(W3[k * 64 + n]);
        }
    }
}

// ======== B1: exclusive scan of each bucket's 391 chunk-counts ========
__global__ __launch_bounds__(512) void k_scan_cols(int* __restrict__ g_hist,
                                                   int* __restrict__ btot) {
    __shared__ int s[512];
    int k = blockIdx.x, t = threadIdx.x;
    int v = (t < CBLK) ? g_hist[k * CBLK + t] : 0;
    s[t] = v;
    for (int o = 1; o < 512; o <<= 1) {
        __syncthreads();
        int xl = (t >= o) ? s[t - o] : 0;
        __syncthreads();
        s[t] += xl;
    }
    __syncthreads();
    if (t < CBLK) g_hist[k * CBLK + t] = s[t] - v;   // exclusive within bucket
    if (t == CBLK - 1) btot[k] = s[t];               // bucket total
}

// ======== B2: exclusive scan of bucket totals -> bucket bases ========
__global__ __launch_bounds__(256) void k_scan_buckets(const int* __restrict__ btot,
                                                      int* __restrict__ bb,
                                                      int* __restrict__ degoff) {
    __shared__ int s[256];
    int t = threadIdx.x;
    int v = (t < NBUC) ? btot[t] : 0;
    s[t] = v;
    for (int o = 1; o < 256; o <<= 1) {
        __syncthreads();
        int xl = (t >= o) ? s[t - o] : 0;
        __syncthreads();
        s[t] += xl;
    }
    __syncthreads();
    if (t < NBUC) bb[t] = s[t] - v;
    if (t == 0) { bb[NBUC] = NE; degoff[NN] = NE; }
}

// ======== C: scatter edges into bucket-sorted order, packed word ========
// packed = (dst&511) << 20 | src   (src < 2^17 fits in 20 bits; 9+20 = 29 bits)
__global__ __launch_bounds__(1024) void k_scatter_edges(
        const int* __restrict__ src, const int* __restrict__ dst,
        const int* __restrict__ g_hist, const int* __restrict__ bb,
        int* __restrict__ sed) {
    __shared__ int cur[NBUC];
    int b = blockIdx.x, t = threadIdx.x;
    if (t < NBUC) cur[t] = bb[t] + g_hist[t * CBLK + b];
    __syncthreads();
    int e0 = b * AEPB;
#pragma unroll
    for (int j = 0; j < 4; ++j) {
        int e = e0 + t + j * 1024;
        if (e < NE) {
            int d = __builtin_nontemporal_load(&dst[e]);
            int s = __builtin_nontemporal_load(&src[e]);
            int p = atomicAdd(&cur[d >> 9], 1);
            sed[p] = ((d & 511) << 20) | s;   // stays in L2 -- D re-reads next
        }
    }
}

// ======== D: per-bucket count + scan + CSR fill + degoff/dinv + xs scale ========
__global__ __launch_bounds__(1024) void k_bucket_csr(
        const int* __restrict__ sed, const int* __restrict__ bb,
        int* __restrict__ csr, int* __restrict__ degoff,
        float* __restrict__ dinv, unsigned short* __restrict__ xs) {
    __shared__ int cnt[512], off[512];
    __shared__ float sdv[512];
    int k = blockIdx.x, t = threadIdx.x;
    int n0 = k << 9;
    int ebeg = bb[k], eend = bb[k + 1];
    if (t < 512) cnt[t] = 0;
    __syncthreads();
    for (int e = ebeg + t; e < eend; e += 1024)
        atomicAdd(&cnt[((unsigned)sed[e]) >> 20], 1);
    __syncthreads();
    int c = (t < 512) ? cnt[t] : 0;
    if (t < 512) off[t] = c;
    for (int o = 1; o < 512; o <<= 1) {
        __syncthreads();
        int xl = (t < 512 && t >= o) ? off[t - o] : 0;
        __syncthreads();
        if (t < 512) off[t] += xl;
    }
    __syncthreads();
    if (t < 512) {
        int excl = off[t] - c;           // exclusive within bucket
        float d = rsqrtf((float)c + 1.0f);
        sdv[t] = d;
        int n = n0 + t;
        if (n < NN) {
            degoff[n] = ebeg + excl;
            dinv[n] = d;
        }
        cnt[t] = excl;                   // becomes cursor
    }
    __syncthreads();
    for (int e = ebeg + t; e < eend; e += 1024) {
        unsigned v = (unsigned)sed[e];
        int p = atomicAdd(&cnt[v >> 20], 1);
        csr[ebeg + p] = v & 0xFFFFF;     // 32KB window per bucket: L2-local
    }
    // scale this bucket's xs rows in place: xs[n][:] *= dinv[n]
    // 512 rows x 8 uint4 = 4096 uint4; 1024 threads -> 4 each.
    for (int i = t; i < 4096; i += 1024) {
        int r = i >> 3;                  // row within bucket
        int n = n0 + r;
        if (n >= NN) break;              // rows are ascending in i
        float d = sdv[r];
        uint4* p = (uint4*)(xs + (size_t)n * 64) + (i & 7);
        uint4 v = *p;
        float2 q0 = unpack2f(v.x), q1 = unpack2f(v.y);
        float2 q2 = unpack2f(v.z), q3 = unpack2f(v.w);
        v.x = pack2f(q0.x * d, q0.y * d);
        v.y = pack2f(q1.x * d, q1.y * d);
        v.z = pack2f(q2.x * d, q2.y * d);
        v.w = pack2f(q3.x * d, q3.y * d);
        *p = v;
    }
}

// ======== 64-wide gather (pre-scaled xs): agg = (sum xs[s] + xs[n]) * dinv[n] ========
__global__ __launch_bounds__(256) void k_gather64_f16(
        const unsigned short* __restrict__ xs, const int* __restrict__ off,
        const int* __restrict__ csr, const float* __restrict__ dinv,
        unsigned short* __restrict__ agg) {
    int n = blockIdx.x * 4 + (threadIdx.x >> 6);
    if (n >= NN) return;
    int lane = threadIdx.x & 63;

    int beg = off[n], end = off[n + 1];
    float a0 = 0.f, a1 = 0.f, a2 = 0.f, a3 = 0.f;
    int e = beg;
    for (; e + 8 <= end; e += 8) {
        int s0 = csr[e],     s1 = csr[e + 1], s2 = csr[e + 2], s3 = csr[e + 3];
        int s4 = csr[e + 4], s5 = csr[e + 5], s6 = csr[e + 6], s7 = csr[e + 7];
        unsigned short u0 = xs[(size_t)s0 * 64 + lane];
        unsigned short u1 = xs[(size_t)s1 * 64 + lane];
        unsigned short u2 = xs[(size_t)s2 * 64 + lane];
        unsigned short u3 = xs[(size_t)s3 * 64 + lane];
        unsigned short u4 = xs[(size_t)s4 * 64 + lane];
        unsigned short u5 = xs[(size_t)s5 * 64 + lane];
        unsigned short u6 = xs[(size_t)s6 * 64 + lane];
        unsigned short u7 = xs[(size_t)s7 * 64 + lane];
        a0 += unpack1f(u0); a1 += unpack1f(u1);
        a2 += unpack1f(u2); a3 += unpack1f(u3);
        a0 += unpack1f(u4); a1 += unpack1f(u5);
        a2 += unpack1f(u6); a3 += unpack1f(u7);
    }
    for (; e + 2 <= end; e += 2) {
        a0 += unpack1f(xs[(size_t)csr[e] * 64 + lane]);
        a1 += unpack1f(xs[(size_t)csr[e + 1] * 64 + lane]);
    }
    if (e < end) a0 += unpack1f(xs[(size_t)csr[e] * 64 + lane]);

    float v = (a0 + a1 + a2 + a3 + unpack1f(xs[(size_t)n * 64 + lane])) * dinv[n];
    agg[(size_t)n * 64 + lane] = pack1f(v);
}

// ======== 128-wide gather, fp16 in -> fp16 agg (unroll 8) ========
__global__ __launch_bounds__(256) void k_gather128_f16(
        const unsigned short* __restrict__ h1, const int* __restrict__ off,
        const int* __restrict__ csr, const float* __restrict__ dinv,
        unsigned short* __restrict__ agg) {
    int n = blockIdx.x * 4 + (threadIdx.x >> 6);
    if (n >= NN) return;
    int lane = threadIdx.x & 63;
    const unsigned int* h = (const unsigned int*)h1;   // half2 per lane

    int beg = off[n], end = off[n + 1];
    float ax = 0.f, ay = 0.f, bx = 0.f, by = 0.f;
    float cx = 0.f, cy = 0.f, dx = 0.f, dy = 0.f;
    int e = beg;
    for (; e + 8 <= end; e += 8) {
        int s0 = csr[e],     s1 = csr[e + 1], s2 = csr[e + 2], s3 = csr[e + 3];
        int s4 = csr[e + 4], s5 = csr[e + 5], s6 = csr[e + 6], s7 = csr[e + 7];
        unsigned int u0 = h[(size_t)s0 * 64 + lane];
        unsigned int u1 = h[(size_t)s1 * 64 + lane];
        unsigned int u2 = h[(size_t)s2 * 64 + lane];
        unsigned int u3 = h[(size_t)s3 * 64 + lane];
        unsigned int u4 = h[(size_t)s4 * 64 + lane];
        unsigned int u5 = h[(size_t)s5 * 64 + lane];
        unsigned int u6 = h[(size_t)s6 * 64 + lane];
        unsigned int u7 = h[(size_t)s7 * 64 + lane];
        float2 v0 = unpack2f(u0), v1 = unpack2f(u1), v2 = unpack2f(u2), v3 = unpack2f(u3);
        float2 v4 = unpack2f(u4), v5 = unpack2f(u5), v6 = unpack2f(u6), v7 = unpack2f(u7);
        ax += v0.x; ay += v0.y;  bx += v1.x; by += v1.y;
        cx += v2.x; cy += v2.y;  dx += v3.x; dy += v3.y;
        ax += v4.x; ay += v4.y;  bx += v5.x; by += v5.y;
        cx += v6.x; cy += v6.y;  dx += v7.x; dy += v7.y;
    }
    for (; e + 2 <= end; e += 2) {
        float2 v0 = unpack2f(h[(size_t)csr[e] * 64 + lane]);
        float2 v1 = unpack2f(h[(size_t)csr[e + 1] * 64 + lane]);
        ax += v0.x; ay += v0.y;  bx += v1.x; by += v1.y;
    }
    if (e < end) {
        float2 v0 = unpack2f(h[(size_t)csr[e] * 64 + lane]);
        ax += v0.x; ay += v0.y;
    }
    float2 self = unpack2f(h[(size_t)n * 64 + lane]);
    float dn = dinv[n];
    ((unsigned int*)agg)[(size_t)n * 64 + lane] =
        pack2f((ax + bx + cx + dx + self.x) * dn,
               (ay + by + cy + dy + self.y) * dn);
}

// ======== MFMA GEMM: out = epilogue(agg @ W) ========
template <int K, int M, int EPI>
__global__ __launch_bounds__(256) void k_gemm_mfma(
        const unsigned short* __restrict__ A, const unsigned short* __restrict__ Wf,
        const float* __restrict__ dinv, const float* __restrict__ bias,
        const float* __restrict__ g, const float* __restrict__ be,
        const float* __restrict__ mn, const float* __restrict__ vr,
        unsigned short* __restrict__ outp) {
    constexpr int KS = K / 32;
    constexpr int CT = M / 16;
    __shared__ __align__(16) unsigned short sWf[CT * KS * 64 * 8];
    __shared__ float sSc[M], sSh[M];

    int tid = threadIdx.x;
    {
        const uint4* s = (const uint4*)Wf;
        uint4* d = (uint4*)sWf;
        constexpr int W4 = CT * KS * 64;
#pragma unroll
        for (int i = tid; i < W4; i += 256) d[i] = s[i];
    }
    if constexpr (EPI == 1 || EPI == 2) {
        for (int c = tid; c < M; c += 256) {
            float s = g[c] * rsqrtf(vr[c] + BN_EPS);
            sSc[c] = s;
            sSh[c] = (bias[c] - mn[c]) * s + be[c];
        }
    }
    __syncthreads();

    int wave = tid >> 6, lane = tid & 63;
    int row0 = blockIdx.x * 64 + wave * 16;
    if (row0 >= NN) return;
    int r  = row0 + (lane & 15);
    int kq = lane >> 4;

    f16x8 bf[KS];
#pragma unroll
    for (int ks = 0; ks < KS; ++ks)
        bf[ks] = *(const f16x8*)(A + (size_t)r * K + ks * 32 + kq * 8);

    float dr = dinv[r];
    const f16x8* wfp = (const f16x8*)sWf;
#pragma unroll
    for (int ct = 0; ct < CT; ++ct) {
        f32x4 acc = {0.f, 0.f, 0.f, 0.f};
#pragma unroll
        for (int ks = 0; ks < KS; ++ks)
            acc = __builtin_amdgcn_mfma_f32_16x16x32_f16(
                wfp[(ct * KS + ks) * 64 + lane], bf[ks], acc, 0, 0, 0);

        int c4 = ct * 16 + kq * 4;
        unsigned short* op = outp + (size_t)r * M + c4;
        if constexpr (EPI == 1 || EPI == 2) {
            float v0 = fmaxf(acc[0] * sSc[c4 + 0] + sSh[c4 + 0], 0.f);
            float v1 = fmaxf(acc[1] * sSc[c4 + 1] + sSh[c4 + 1], 0.f);
            float v2 = fmaxf(acc[2] * sSc[c4 + 2] + sSh[c4 + 2], 0.f);
            float v3 = fmaxf(acc[3] * sSc[c4 + 3] + sSh[c4 + 3], 0.f);
            if constexpr (EPI == 1) { v0 *= dr; v1 *= dr; v2 *= dr; v3 *= dr; }
            uint2 o; o.x = pack2f(v0, v1); o.y = pack2f(v2, v3);
            *(uint2*)op = o;
        } else {
            uint2 o;
            o.x = pack2f(acc[0] * dr, acc[1] * dr);
            o.y = pack2f(acc[2] * dr, acc[3] * dr);
            *(uint2*)op = o;
        }
    }
}

// ======== final: gather fp16 + b3 + ReLU + (·Wo + bo) ========
__global__ __launch_bounds__(256) void k_gather_final_f16(
        const unsigned short* __restrict__ hs, const int* __restrict__ off,
        const int* __restrict__ csr, const float* __restrict__ dinv,
        const float* __restrict__ b, const float* __restrict__ Wo,
        const float* __restrict__ bo, float* __restrict__ out) {
    int n = blockIdx.x * 4 + (threadIdx.x >> 6);
    if (n >= NN) return;
    int lane = threadIdx.x & 63;

    int beg = off[n], end = off[n + 1];
    float a0 = 0.f, a1 = 0.f, a2 = 0.f, a3 = 0.f;
    int e = beg;
    for (; e + 8 <= end; e += 8) {
        int s0 = csr[e],     s1 = csr[e + 1], s2 = csr[e + 2], s3 = csr[e + 3];
        int s4 = csr[e + 4], s5 = csr[e + 5], s6 = csr[e + 6], s7 = csr[e + 7];
        a0 += unpack1f(hs[(size_t)s0 * 64 + lane]);
        a1 += unpack1f(hs[(size_t)s1 * 64 + lane]);
        a2 += unpack1f(hs[(size_t)s2 * 64 + lane]);
        a3 += unpack1f(hs[(size_t)s3 * 64 + lane]);
        a0 += unpack1f(hs[(size_t)s4 * 64 + lane]);
        a1 += unpack1f(hs[(size_t)s5 * 64 + lane]);
        a2 += unpack1f(hs[(size_t)s6 * 64 + lane]);
        a3 += unpack1f(hs[(size_t)s7 * 64 + lane]);
    }
    for (; e + 2 <= end; e += 2) {
        a0 += unpack1f(hs[(size_t)csr[e] * 64 + lane]);
        a1 += unpack1f(hs[(size_t)csr[e + 1] * 64 + lane]);
    }
    if (e < end) a0 += unpack1f(hs[(size_t)csr[e] * 64 + lane]);

    float val = (a0 + a1 + a2 + a3 + unpack1f(hs[(size_t)n * 64 + lane])) * dinv[n]
                + b[lane];
    val = fmaxf(val, 0.f) * Wo[lane];
#pragma unroll
    for (int o = 32; o > 0; o >>= 1) val += __shfl_down(val, o, 64);
    if (lane == 0) out[n] = val + bo[0];
}

extern "C" void kernel_launch(void* const* d_in, const int* in_sizes, int n_in,
                              void* d_out, int out_size, void* d_ws, size_t ws_size,
                              hipStream_t stream) {
    const float* x   = (const float*)d_in[0];
    const int*   ei  = (const int*)d_in[1];
    const int*   src = ei;
    const int*   dst = ei + NE;
    const float* W1  = (const float*)d_in[2];
    const float* b1  = (const float*)d_in[3];
    const float* g1  = (const float*)d_in[4];
    const float* be1 = (const float*)d_in[5];
    const float* m1  = (const float*)d_in[6];
    const float* v1  = (const float*)d_in[7];
    const float* W2  = (const float*)d_in[8];
    const float* b2  = (const float*)d_in[9];
    const float* g2  = (const float*)d_in[10];
    const float* be2 = (const float*)d_in[11];
    const float* m2  = (const float*)d_in[12];
    const float* v2  = (const float*)d_in[13];
    const float* W3  = (const float*)d_in[14];
    const float* b3  = (const float*)d_in[15];
    const float* Wo  = (const float*)d_in[16];
    const float* bo  = (const float*)d_in[17];
    float* out = (float*)d_out;

    char* ws = (char*)d_ws;
    float* dinv   = (float*)(ws + 0);                // 400,000 B
    int*   degoff = (int*)(ws + 400032);             // (N+1) ints
    int*   bb     = (int*)(ws + 800064);             // NBUC+1 ints
    int*   btot   = (int*)(ws + 801088);             // NBUC ints
    int*   g_hist = (int*)(ws + 801920);             // NBUC*CBLK ints = 306,544 B
    unsigned short* Wf1 = (unsigned short*)(ws + 1108480);  // 16,384 B
    unsigned short* Wf2 = (unsigned short*)(ws + 1124864);  // 32,768 B
    unsigned short* Wf3 = (unsigned short*)(ws + 1157632);  // 16,384 B -> 1,174,016
    int*   csr    = (int*)(ws + 1174016);            // 6,400,000 B -> 7,574,016
    char*  S1     = ws + 7574016;                    // 51.2 MB: xs(f16) -> h1ps(f16) -> h2p(f16)
    char*  S2     = ws + 58774016;                   // 51.2 MB: sed -> aggX -> aggH1 -> hs3

    unsigned short* xs    = (unsigned short*)S1;
    unsigned short* h1ps  = (unsigned short*)S1;
    unsigned short* h2p   = (unsigned short*)S1;
    int*            sed   = (int*)S2;                // 6.4 MB packed edges (dead after D)
    unsigned short* aggX  = (unsigned short*)S2;
    unsigned short* aggH1 = (unsigned short*)S2;
    unsigned short* hs3   = (unsigned short*)S2;

    int gW = (NN + 3) / 4;
    int gG = (NN + 63) / 64;

    // ---- atomic-free CSR build: hist -> scans -> scatter(packed) -> per-bucket fill+scale ----
    k_hist_cast<<<CBLK + XS_BLOCKS + WPREP_BLOCKS, 1024, 0, stream>>>(
        dst, g_hist, x, xs, W1, W2, W3, Wf1, Wf2, Wf3);
    k_scan_cols<<<NBUC, 512, 0, stream>>>(g_hist, btot);
    k_scan_buckets<<<1, 256, 0, stream>>>(btot, bb, degoff);
    k_scatter_edges<<<CBLK, 1024, 0, stream>>>(src, dst, g_hist, bb, sed);
    k_bucket_csr<<<NBUC, 1024, 0, stream>>>(sed, bb, csr, degoff, dinv, xs);

    // ---- layer 1: gather(xs pre-scaled) ; MFMA GEMM1 + BN + ReLU + *dinv ----
    k_gather64_f16<<<gW, 256, 0, stream>>>(xs, degoff, csr, dinv, aggX);
    k_gemm_mfma<64, 128, 1><<<gG, 256, 0, stream>>>(
        aggX, Wf1, dinv, b1, g1, be1, m1, v1, h1ps);

    // ---- layer 2: gather(h1ps) ; MFMA GEMM2 + BN + ReLU ----
    k_gather128_f16<<<gW, 256, 0, stream>>>(h1ps, degoff, csr, dinv, aggH1);
    k_gemm_mfma<128, 128, 2><<<gG, 256, 0, stream>>>(
        aggH1, Wf2, dinv, b2, g2, be2, m2, v2, h2p);

    // ---- layer 3: MFMA GEMM3 (*dinv) ; final gather + dot ----
    k_gemm_mfma<128, 64, 3><<<gG, 256, 0, stream>>>(
        h2p, Wf3, dinv, nullptr, nullptr, nullptr, nullptr, nullptr, hs3);
    k_gather_final_f16<<<gW, 256, 0, stream>>>(hs3, degoff, csr, dinv,
                                               b3, Wo, bo, out);
}